// Round 2
// baseline (3664.747 us; speedup 1.0000x reference)
//
#include <hip/hip_runtime.h>

// LSTM autoencoder, fp32, B=T=512. One block per sequence.
// Key idea: xh (x_t | h_{t-1}) is wave-uniform -> keep it lane-distributed in
// VGPRs and broadcast via v_readlane into an SGPR feeding v_fmac (1 SGPR/VALU op
// is legal). This removes the per-wave ds_read_b128 broadcast storm that made
// R0 LDS-pipe-bound (VALUBusy 36%, ~4900 cyc/step on d2).
// Per step: gate dot (readlane+FMA) -> activate -> ds_write gates -> ONE barrier
// -> every wave redundantly reads gates + updates h,c (lane-distributed, so the
// next step's readlanes find h in-register). Gates double-buffered in LDS.

#define B_ 512
#define T_ 512

__device__ __forceinline__ float fast_sigmoid(float x) {
    return 1.0f / (1.0f + __expf(-x));
}
__device__ __forceinline__ float fast_tanh(float x) {
    // 1 - 2/(e^{2x}+1): saturates to +/-1, no NaN.
    return 1.0f - 2.0f / (__expf(2.0f * x) + 1.0f);
}
__device__ __forceinline__ float rl(float v, int lane) {
    return __int_as_float(__builtin_amdgcn_readlane(__float_as_int(v), lane));
}

// NT threads (multiple of 64), NACT of them own GPT gate rows each (NACT*GPT == 4H).
// Row assignment: thread tid owns rows {tid + i*NACT}.
template <int IN, int H, int NT, int NACT, int GPT>
__global__ __launch_bounds__(NT, 1)
void lstm_rl_kernel(const float* __restrict__ x,    // [B,T,IN]
                    const float* __restrict__ Wih,  // [4H,IN]
                    const float* __restrict__ Whh,  // [4H,H]
                    const float* __restrict__ bih,
                    const float* __restrict__ bhh,
                    float* __restrict__ out)        // [B,T,H]
{
    constexpr int G     = 4 * H;
    constexpr int XTAIL = (IN > 64) ? IN - 64 : 0;  // x elements 64..IN-1 (e1: 8)
    constexpr int HTAIL = (H  > 64) ? H  - 64 : 0;  // h units 64..H-1   (d2: 8)
    constexpr int XLO   = (IN < 64) ? IN : 64;
    constexpr int HLO   = (H  < 64) ? H  : 64;

    __shared__ float gbuf[2][G];   // activated gates, double-buffered

    const int tid  = threadIdx.x;
    const int lane = tid & 63;
    const int b    = blockIdx.x;
    const bool act = (tid < NACT);

    // ---- weight rows + bias into registers (one-time) ----
    float w[GPT][IN + H];
    float bias[GPT];
    if (act) {
#pragma unroll
        for (int i = 0; i < GPT; ++i) {
            const int row = tid + i * NACT;
            const float4* wi = reinterpret_cast<const float4*>(Wih + row * IN);
#pragma unroll
            for (int k = 0; k < IN / 4; ++k) {
                float4 v = wi[k];
                w[i][4*k+0] = v.x; w[i][4*k+1] = v.y;
                w[i][4*k+2] = v.z; w[i][4*k+3] = v.w;
            }
            const float4* wh = reinterpret_cast<const float4*>(Whh + row * H);
#pragma unroll
            for (int k = 0; k < H / 4; ++k) {
                float4 v = wh[k];
                w[i][IN+4*k+0] = v.x; w[i][IN+4*k+1] = v.y;
                w[i][IN+4*k+2] = v.z; w[i][IN+4*k+3] = v.w;
            }
            bias[i] = bih[row] + bhh[row];
        }
    }

    // ---- lane-distributed state (per wave, redundantly maintained) ----
    float h0 = 0.0f, c0 = 0.0f;   // h[lane], c[lane]          (lane < HLO)
    float h1 = 0.0f, c1 = 0.0f;   // h[64+lane], c[64+lane]    (lane < HTAIL)

    const float* xb   = x + (size_t)b * T_ * IN;
    float*       outb = out + (size_t)b * T_ * H;

    // x_t lane-distributed: xr0 = x[lane] (lane<XLO), xrt = x[64+lane] (lane<XTAIL)
    float xr0 = 0.0f, xrt = 0.0f;
    if (lane < XLO) xr0 = xb[lane];
    if (XTAIL > 0 && lane < XTAIL) xrt = xb[64 + lane];

    for (int t = 0; t < T_; ++t) {
        // prefetch x_{t+1} (coalesced, L1-hit for waves>0); latency hidden by dot
        float xn0 = 0.0f, xnt = 0.0f;
        if (t + 1 < T_) {
            if (lane < XLO) xn0 = xb[(t + 1) * IN + lane];
            if (XTAIL > 0 && lane < XTAIL) xnt = xb[(t + 1) * IN + 64 + lane];
        }

        if (act) {
            float a[GPT][2];
#pragma unroll
            for (int i = 0; i < GPT; ++i) { a[i][0] = bias[i]; a[i][1] = 0.0f; }

            // x part: slots 0..IN-1
#pragma unroll
            for (int k = 0; k < IN; ++k) {
                float s = rl((k < 64) ? xr0 : xrt, k & 63);
#pragma unroll
                for (int i = 0; i < GPT; ++i) a[i][k & 1] += s * w[i][k];
            }
            // h part: slots IN..IN+H-1
#pragma unroll
            for (int j = 0; j < H; ++j) {
                float s = rl((j < 64) ? h0 : h1, j & 63);
#pragma unroll
                for (int i = 0; i < GPT; ++i) a[i][j & 1] += s * w[i][IN + j];
            }
            // activate + write gates (rows: i[0,H) f[H,2H) g[2H,3H) o[3H,4H))
#pragma unroll
            for (int i = 0; i < GPT; ++i) {
                const int row  = tid + i * NACT;
                const float v  = a[i][0] + a[i][1];
                const bool isg = (row >= 2 * H) && (row < 3 * H);
                // tanh(v) = 2*sigmoid(2v)-1: one exp either way
                float pre = isg ? 2.0f * v : v;
                float sg  = fast_sigmoid(pre);
                gbuf[t & 1][row] = isg ? (2.0f * sg - 1.0f) : sg;
            }
        }
        __syncthreads();

        // ---- redundant per-wave h,c update (predicated on LANE, every wave) ----
        {
            const float* gb = gbuf[t & 1];
            if (lane < HLO) {
                float ig = gb[lane], fg = gb[H + lane];
                float gg = gb[2 * H + lane], og = gb[3 * H + lane];
                c0 = fg * c0 + ig * gg;
                h0 = og * fast_tanh(c0);
                if (tid == lane) outb[t * H + lane] = h0;  // wave 0 stores
            }
            if (HTAIL > 0 && lane < HTAIL) {
                const int u = 64 + lane;
                float ig = gb[u], fg = gb[H + u];
                float gg = gb[2 * H + u], og = gb[3 * H + u];
                c1 = fg * c1 + ig * gg;
                h1 = og * fast_tanh(c1);
                if (tid == lane) outb[t * H + u] = h1;
            }
        }

        xr0 = xn0; xrt = xnt;
    }
}

extern "C" void kernel_launch(void* const* d_in, const int* in_sizes, int n_in,
                              void* d_out, int out_size, void* d_ws, size_t ws_size,
                              hipStream_t stream) {
    const float* x      = (const float*)d_in[0];
    const float* e1_Wih = (const float*)d_in[1];
    const float* e1_Whh = (const float*)d_in[2];
    const float* e1_bih = (const float*)d_in[3];
    const float* e1_bhh = (const float*)d_in[4];
    const float* e2_Wih = (const float*)d_in[5];
    const float* e2_Whh = (const float*)d_in[6];
    const float* e2_bih = (const float*)d_in[7];
    const float* e2_bhh = (const float*)d_in[8];
    const float* d1_Wih = (const float*)d_in[9];
    const float* d1_Whh = (const float*)d_in[10];
    const float* d1_bih = (const float*)d_in[11];
    const float* d1_bhh = (const float*)d_in[12];
    const float* d2_Wih = (const float*)d_in[13];
    const float* d2_Whh = (const float*)d_in[14];
    const float* d2_bih = (const float*)d_in[15];
    const float* d2_bhh = (const float*)d_in[16];

    float* outp = (float*)d_out;
    // ws0 = e2 out [512,512,32] (32 MB); ws1 = d1 out [512,512,64] (64 MB);
    // e1 out (64 MB) borrows d_out as scratch; d2 writes the final output.
    float* ws0 = (float*)d_ws;
    float* ws1 = (float*)((char*)d_ws + (size_t)B_ * T_ * 32 * sizeof(float));

    // e1: 72 -> 64, 256 gates: 128 thr x 2 gates
    lstm_rl_kernel<72, 64, 128, 128, 2><<<B_, 128, 0, stream>>>(
        x, e1_Wih, e1_Whh, e1_bih, e1_bhh, outp);
    // e2: 64 -> 32, 128 gates: 128 thr x 1 gate
    lstm_rl_kernel<64, 32, 128, 128, 1><<<B_, 128, 0, stream>>>(
        outp, e2_Wih, e2_Whh, e2_bih, e2_bhh, ws0);
    // d1: 32 -> 64, 256 gates: 128 thr x 2 gates
    lstm_rl_kernel<32, 64, 128, 128, 2><<<B_, 128, 0, stream>>>(
        ws0, d1_Wih, d1_Whh, d1_bih, d1_bhh, ws1);
    // d2: 64 -> 72, 288 gates: 96 active thr x 3 gates (block padded to 128 so
    // every lane of both waves holds valid x/h for readlane)
    lstm_rl_kernel<64, 72, 128, 96, 3><<<B_, 128, 0, stream>>>(
        ws1, d2_Wih, d2_Whh, d2_bih, d2_bhh, outp);
}

// Round 3
// 3184.298 us; speedup vs baseline: 1.1509x; 1.1509x over previous
//
#include <hip/hip_runtime.h>

// LSTM autoencoder, fp32, B=T=512. One block per sequence, gate-row-per-thread.
// R2: fix R1's VGPR spill (GPT=1 -> <=136 weight floats/thread) and route the
// wave-uniform x_t through uniform (scalar s_load) reads so only the h-part of
// the dot needs v_readlane broadcasts. No divergent control flow: padded
// threads compute a clamped duplicate gate row into padded gbuf slots.

#define B_ 512
#define T_ 512

__device__ __forceinline__ float fast_tanh(float x) {
    // 1 - 2/(e^{2x}+1): saturates to +/-1, no NaN.
    return 1.0f - 2.0f / (__expf(2.0f * x) + 1.0f);
}
__device__ __forceinline__ float rl(float v, int lane) {
    return __int_as_float(__builtin_amdgcn_readlane(__float_as_int(v), lane));
}

// NT threads; gate rows 0..4H-1 owned by tid (padded tids duplicate row 4H-1).
template <int IN, int H, int NT, int MINW>
__global__ __launch_bounds__(NT, MINW)
void lstm_kernel(const float* __restrict__ x,    // [B,T,IN]
                 const float* __restrict__ Wih,  // [4H,IN]
                 const float* __restrict__ Whh,  // [4H,H]
                 const float* __restrict__ bih,
                 const float* __restrict__ bhh,
                 float* __restrict__ out)        // [B,T,H]
{
    constexpr int G     = 4 * H;
    constexpr int IN4   = IN / 4;
    constexpr int HTAIL = (H > 64) ? H - 64 : 0;   // d2: 8
    constexpr int HLO   = (H < 64) ? H : 64;
    static_assert(IN % 4 == 0 && H % 4 == 0, "vec4 layout");

    __shared__ float gbuf[2][NT];   // activated gates (padded), double-buffered

    const int tid  = threadIdx.x;
    const int lane = tid & 63;
    const int b    = blockIdx.x;
    const int row  = (tid < G) ? tid : (G - 1);   // clamp: no divergence

    // ---- weight row + bias into VGPRs (one-time) ----
    float wx[IN], wh[H];
    {
        const float4* wi = reinterpret_cast<const float4*>(Wih + row * IN);
#pragma unroll
        for (int k = 0; k < IN4; ++k) {
            float4 v = wi[k];
            wx[4*k+0] = v.x; wx[4*k+1] = v.y; wx[4*k+2] = v.z; wx[4*k+3] = v.w;
        }
        const float4* wp = reinterpret_cast<const float4*>(Whh + row * H);
#pragma unroll
        for (int k = 0; k < H / 4; ++k) {
            float4 v = wp[k];
            wh[4*k+0] = v.x; wh[4*k+1] = v.y; wh[4*k+2] = v.z; wh[4*k+3] = v.w;
        }
    }
    const float bias = bih[row] + bhh[row];
    const bool  isg  = (row >= 2 * H) && (row < 3 * H);   // tanh gate rows

    // lane-distributed recurrent state, redundantly maintained per wave
    float h0 = 0.0f, c0 = 0.0f;                 // unit = lane      (lane < HLO)
    float h1 = 0.0f, c1 = 0.0f;                 // unit = 64 + lane (lane < HTAIL)

    const float4* xrow = reinterpret_cast<const float4*>(x + (size_t)b * T_ * IN);
    float*        outb = out + (size_t)b * T_ * H;

    for (int t = 0; t < T_; ++t) {
        // ---- wave-uniform x_t load (uniform CF + __restrict__ -> s_load) ----
        float4 xv[IN4];
#pragma unroll
        for (int k = 0; k < IN4; ++k) xv[k] = xrow[k];
        xrow += IN4;

        // ---- gate dot: h-part via readlane (latency of x loads hides here) ----
        float a0 = bias, a1 = 0.0f;
#pragma unroll
        for (int j = 0; j < H; ++j) {
            float s = rl((j < 64) ? h0 : h1, j & 63);
            if (j & 1) a1 += s * wh[j]; else a0 += s * wh[j];
        }
        // ---- x-part: splat (SGPR) operand FMAs ----
#pragma unroll
        for (int k = 0; k < IN4; ++k) {
            a0 += xv[k].x * wx[4*k+0];
            a1 += xv[k].y * wx[4*k+1];
            a0 += xv[k].z * wx[4*k+2];
            a1 += xv[k].w * wx[4*k+3];
        }
        const float v = a0 + a1;
        // sigmoid(v) or tanh(v)=2*sigmoid(2v)-1: one exp either way
        const float pre = isg ? 2.0f * v : v;
        const float sg  = 1.0f / (1.0f + __expf(-pre));
        gbuf[t & 1][tid] = isg ? (2.0f * sg - 1.0f) : sg;

        __syncthreads();   // single barrier; double-buffered gbuf makes it safe

        // ---- redundant per-wave h,c update (rows: i[0,H) f[H,2H) g[2H,3H) o[3H,4H)) ----
        const float* gb = gbuf[t & 1];
        if (lane < HLO) {
            float ig = gb[lane], fg = gb[H + lane];
            float gg = gb[2 * H + lane], og = gb[3 * H + lane];
            c0 = fg * c0 + ig * gg;
            h0 = og * fast_tanh(c0);
            if (tid == lane) outb[(size_t)t * H + lane] = h0;   // wave 0 stores
        }
        if constexpr (HTAIL > 0) {
            if (lane < HTAIL) {
                const int u = 64 + lane;
                float ig = gb[u], fg = gb[H + u];
                float gg = gb[2 * H + u], og = gb[3 * H + u];
                c1 = fg * c1 + ig * gg;
                h1 = og * fast_tanh(c1);
                if (tid == lane) outb[(size_t)t * H + u] = h1;
            }
        }
    }
}

extern "C" void kernel_launch(void* const* d_in, const int* in_sizes, int n_in,
                              void* d_out, int out_size, void* d_ws, size_t ws_size,
                              hipStream_t stream) {
    const float* x      = (const float*)d_in[0];
    const float* e1_Wih = (const float*)d_in[1];
    const float* e1_Whh = (const float*)d_in[2];
    const float* e1_bih = (const float*)d_in[3];
    const float* e1_bhh = (const float*)d_in[4];
    const float* e2_Wih = (const float*)d_in[5];
    const float* e2_Whh = (const float*)d_in[6];
    const float* e2_bih = (const float*)d_in[7];
    const float* e2_bhh = (const float*)d_in[8];
    const float* d1_Wih = (const float*)d_in[9];
    const float* d1_Whh = (const float*)d_in[10];
    const float* d1_bih = (const float*)d_in[11];
    const float* d1_bhh = (const float*)d_in[12];
    const float* d2_Wih = (const float*)d_in[13];
    const float* d2_Whh = (const float*)d_in[14];
    const float* d2_bih = (const float*)d_in[15];
    const float* d2_bhh = (const float*)d_in[16];

    float* outp = (float*)d_out;
    // ws0 = e2 out [512,512,32] (32 MB); ws1 = d1 out [512,512,64] (64 MB);
    // e1 out (64 MB) borrows d_out as scratch; d2 writes the final output.
    float* ws0 = (float*)d_ws;
    float* ws1 = (float*)((char*)d_ws + (size_t)B_ * T_ * 32 * sizeof(float));

    // e1: 72 -> 64 (G=256) : 256 thr, weights 136/thread
    lstm_kernel<72, 64, 256, 2><<<B_, 256, 0, stream>>>(
        x, e1_Wih, e1_Whh, e1_bih, e1_bhh, outp);
    // e2: 64 -> 32 (G=128) : 128 thr, weights 96/thread
    lstm_kernel<64, 32, 128, 2><<<B_, 128, 0, stream>>>(
        outp, e2_Wih, e2_Whh, e2_bih, e2_bhh, ws0);
    // d1: 32 -> 64 (G=256) : 256 thr, weights 96/thread
    lstm_kernel<32, 64, 256, 2><<<B_, 256, 0, stream>>>(
        ws0, d1_Wih, d1_Whh, d1_bih, d1_bhh, ws1);
    // d2: 64 -> 72 (G=288) : 320 thr (32 padded), weights 136/thread;
    // min 3 waves/EU caps VGPR ~170 so 2 blocks/CU (10 waves) stay resident.
    lstm_kernel<64, 72, 320, 3><<<B_, 320, 0, stream>>>(
        ws1, d2_Wih, d2_Whh, d2_bih, d2_bhh, outp);
}

// Round 4
// 2940.148 us; speedup vs baseline: 1.2464x; 1.0830x over previous
//
#include <hip/hip_runtime.h>

// LSTM autoencoder, fp32 in/out, B=T=512. One block per sequence, gate-row-per-
// thread. R3: packed-fp16 dot (v_dot2_f32_f16, fp32 accumulate) halves both the
// weight-register footprint (R1/R2 died of VGPR spill: 136 fp32 weights/thread)
// and the readlane-broadcast count. x_t and h_{t-1} live as half2 pairs, lane-
// distributed, broadcast via v_readlane; h pairs rebuilt each step from a tiny
// per-wave LDS buffer (intra-wave dep, no barrier). One __syncthreads per step,
// activated gates double-buffered in LDS. c, gates, accumulation all fp32.

#define B_ 512
#define T_ 512

typedef _Float16 h2_t __attribute__((ext_vector_type(2)));

#if __has_builtin(__builtin_amdgcn_fdot2)
#define DOT2(w, s, a) __builtin_amdgcn_fdot2((w), (s), (a), false)
#else
#define DOT2(w, s, a) ((a) + (float)(w).x * (float)(s).x + (float)(w).y * (float)(s).y)
#endif

__device__ __forceinline__ float fast_tanh(float x) {
    // 1 - 2/(e^{2x}+1): saturates to +/-1, no NaN.
    return 1.0f - 2.0f / (__expf(2.0f * x) + 1.0f);
}
__device__ __forceinline__ h2_t rlh2(h2_t v, int l) {
    return __builtin_bit_cast(h2_t,
        __builtin_amdgcn_readlane(__builtin_bit_cast(int, v), l));
}
__device__ __forceinline__ h2_t pack2(float a, float b) {
    h2_t p; p.x = (_Float16)a; p.y = (_Float16)b; return p;
}

// NT threads; gate rows 0..4H-1 owned by tid (padded tids duplicate row 4H-1).
template <int IN, int H, int NT, int MINW>
__global__ __launch_bounds__(NT, MINW)
void lstm_h2_kernel(const float* __restrict__ x,    // [B,T,IN]
                    const float* __restrict__ Wih,  // [4H,IN]
                    const float* __restrict__ Whh,  // [4H,H]
                    const float* __restrict__ bih,
                    const float* __restrict__ bhh,
                    float* __restrict__ out)        // [B,T,H]
{
    constexpr int G   = 4 * H;
    constexpr int XP  = IN / 2;                 // x pairs
    constexpr int HP  = H / 2;                  // h pairs
    constexpr int NW  = NT / 64;
    constexpr int HLO = (H < 64) ? H : 64;
    constexpr int HT  = (H > 64) ? H - 64 : 0;  // d2: 8
    static_assert(IN % 2 == 0 && H % 2 == 0, "pair layout");

    __shared__ float gbuf[2][NT];               // activated gates, double-buffered
    __shared__ __align__(16) float hbuf[NW][H]; // per-wave h (no cross-wave use)

    const int tid  = threadIdx.x;
    const int lane = tid & 63;
    const int wv   = tid >> 6;
    const int b    = blockIdx.x;
    const int row  = (tid < G) ? tid : (G - 1);   // clamp: no divergence

    // ---- weight row packed to half2 (one-time; ~68 VGPRs) ----
    h2_t wx[XP], wh[HP];
    {
        const float2* wi = reinterpret_cast<const float2*>(Wih + (size_t)row * IN);
#pragma unroll
        for (int k = 0; k < XP; ++k) { float2 v = wi[k]; wx[k] = pack2(v.x, v.y); }
        const float2* wp = reinterpret_cast<const float2*>(Whh + (size_t)row * H);
#pragma unroll
        for (int k = 0; k < HP; ++k) { float2 v = wp[k]; wh[k] = pack2(v.x, v.y); }
    }
    const float bias = bih[row] + bhh[row];
    const bool  isg  = (row >= 2 * H) && (row < 3 * H);   // tanh gate rows

    // lane-distributed recurrent state (c fp32 in regs; h round-trips via hbuf)
    float c0 = 0.0f, c1 = 0.0f;
    if (lane < HLO) hbuf[wv][lane] = 0.0f;
    if (HT > 0 && lane < HT) hbuf[wv][64 + lane] = 0.0f;

    const float2* xrow = reinterpret_cast<const float2*>(x + (size_t)b * T_ * IN);
    float*        outb = out + (size_t)b * T_ * H;

    // x_0 pairs: lane l < XP holds (x[2l], x[2l+1]) packed
    h2_t xp;
    {
        float2 v = (lane < XP) ? xrow[lane] : float2{0.0f, 0.0f};
        xp = pack2(v.x, v.y);
    }

    for (int t = 0; t < T_; ++t) {
        // h pairs from per-wave hbuf (intra-wave dependency only; lgkmcnt handles)
        h2_t hp;
        {
            const float2* hb2 = reinterpret_cast<const float2*>(hbuf[wv]);
            float2 v = (lane < HP) ? hb2[lane] : float2{0.0f, 0.0f};
            hp = pack2(v.x, v.y);
        }
        // prefetch x_{t+1} pairs (coalesced 8B; latency hidden by the dot)
        float2 xnv = {0.0f, 0.0f};
        if (t + 1 < T_ && lane < XP) xnv = xrow[(t + 1) * XP + lane];

        // ---- gate dot: readlane-broadcast pairs + dot2 (fp32 accumulate) ----
        float a0 = bias, a1 = 0.0f;
#pragma unroll
        for (int j = 0; j < XP; ++j) {
            h2_t s = rlh2(xp, j);
            if (j & 1) a1 = DOT2(wx[j], s, a1); else a0 = DOT2(wx[j], s, a0);
        }
#pragma unroll
        for (int j = 0; j < HP; ++j) {
            h2_t s = rlh2(hp, j);
            if (j & 1) a1 = DOT2(wh[j], s, a1); else a0 = DOT2(wh[j], s, a0);
        }
        const float v = a0 + a1;
        // sigmoid(v) or tanh(v)=2*sigmoid(2v)-1: one exp either way
        const float pre = isg ? 2.0f * v : v;
        const float sg  = 1.0f / (1.0f + __expf(-pre));
        gbuf[t & 1][tid] = isg ? (2.0f * sg - 1.0f) : sg;

        __syncthreads();   // single barrier; double-buffered gbuf makes it safe

        // ---- redundant per-wave h,c update (rows: i[0,H) f[H,2H) g[2H,3H) o[3H,4H)) ----
        const float* gb = gbuf[t & 1];
        if (lane < HLO) {
            float ig = gb[lane], fg = gb[H + lane];
            float gg = gb[2 * H + lane], og = gb[3 * H + lane];
            c0 = fg * c0 + ig * gg;
            float hv = og * fast_tanh(c0);
            hbuf[wv][lane] = hv;
            if (tid == lane) outb[(size_t)t * H + lane] = hv;   // wave 0 stores
        }
        if constexpr (HT > 0) {
            if (lane < HT) {
                const int u = 64 + lane;
                float ig = gb[u], fg = gb[H + u];
                float gg = gb[2 * H + u], og = gb[3 * H + u];
                c1 = fg * c1 + ig * gg;
                float hv = og * fast_tanh(c1);
                hbuf[wv][u] = hv;
                if (tid == lane) outb[(size_t)t * H + u] = hv;
            }
        }
        xp = pack2(xnv.x, xnv.y);
    }
}

extern "C" void kernel_launch(void* const* d_in, const int* in_sizes, int n_in,
                              void* d_out, int out_size, void* d_ws, size_t ws_size,
                              hipStream_t stream) {
    const float* x      = (const float*)d_in[0];
    const float* e1_Wih = (const float*)d_in[1];
    const float* e1_Whh = (const float*)d_in[2];
    const float* e1_bih = (const float*)d_in[3];
    const float* e1_bhh = (const float*)d_in[4];
    const float* e2_Wih = (const float*)d_in[5];
    const float* e2_Whh = (const float*)d_in[6];
    const float* e2_bih = (const float*)d_in[7];
    const float* e2_bhh = (const float*)d_in[8];
    const float* d1_Wih = (const float*)d_in[9];
    const float* d1_Whh = (const float*)d_in[10];
    const float* d1_bih = (const float*)d_in[11];
    const float* d1_bhh = (const float*)d_in[12];
    const float* d2_Wih = (const float*)d_in[13];
    const float* d2_Whh = (const float*)d_in[14];
    const float* d2_bih = (const float*)d_in[15];
    const float* d2_bhh = (const float*)d_in[16];

    float* outp = (float*)d_out;
    // ws0 = e2 out [512,512,32] (32 MB); ws1 = d1 out [512,512,64] (64 MB);
    // e1 out (64 MB) borrows d_out as scratch; d2 writes the final output.
    float* ws0 = (float*)d_ws;
    float* ws1 = (float*)((char*)d_ws + (size_t)B_ * T_ * 32 * sizeof(float));

    // e1: 72 -> 64 (G=256): 256 thr, 8 waves/CU resident
    lstm_h2_kernel<72, 64, 256, 2><<<B_, 256, 0, stream>>>(
        x, e1_Wih, e1_Whh, e1_bih, e1_bhh, outp);
    // e2: 64 -> 32 (G=128): 128 thr
    lstm_h2_kernel<64, 32, 128, 2><<<B_, 128, 0, stream>>>(
        outp, e2_Wih, e2_Whh, e2_bih, e2_bhh, ws0);
    // d1: 32 -> 64 (G=256): 256 thr
    lstm_h2_kernel<32, 64, 256, 2><<<B_, 256, 0, stream>>>(
        ws0, d1_Wih, d1_Whh, d1_bih, d1_bhh, ws1);
    // d2: 64 -> 72 (G=288): 320 thr (32 padded); minwaves=3 caps VGPR at 170 so
    // both 5-wave blocks stay resident (3+3+2+2 waves/SIMD); need ~100 VGPR.
    lstm_h2_kernel<64, 72, 320, 3><<<B_, 320, 0, stream>>>(
        ws1, d2_Wih, d2_Whh, d2_bih, d2_bhh, outp);
}